// Round 17
// baseline (209.163 us; speedup 1.0000x reference)
//
#include <hip/hip_runtime.h>

#define T_SEQ 2048
#define D_MODEL 2048
#define NH 16
#define NKV 4
#define HEAD_DIM 128

typedef unsigned short u16;
typedef __attribute__((ext_vector_type(8))) short bf16x8;
typedef __attribute__((ext_vector_type(4))) float f32x4;

__device__ __forceinline__ float bf2f(u16 u) { return __uint_as_float(((unsigned)u) << 16); }
__device__ __forceinline__ u16 f2bf(float f) {
  unsigned x = __float_as_uint(f);
  return (u16)((x + 0x7FFFu + ((x >> 16) & 1u)) >> 16);
}
__device__ __forceinline__ float fexp2(float x) { return __builtin_amdgcn_exp2f(x); }

#define ASYNC_COPY16(g, l)                                                        \
  __builtin_amdgcn_global_load_lds((const __attribute__((address_space(1))) unsigned int*)(g), \
                                   (__attribute__((address_space(3))) unsigned int*)(l), 16, 0, 0)

#define BARRIER() do { asm volatile("" ::: "memory"); __builtin_amdgcn_s_barrier(); asm volatile("" ::: "memory"); } while (0)

template<int N> __device__ __forceinline__ void vmwait() {
  if constexpr (N == 0) asm volatile("s_waitcnt vmcnt(0)" ::: "memory");
  else if constexpr (N == 3) asm volatile("s_waitcnt vmcnt(3)" ::: "memory");
  else if constexpr (N == 4) asm volatile("s_waitcnt vmcnt(4)" ::: "memory");
  else if constexpr (N == 5) asm volatile("s_waitcnt vmcnt(5)" ::: "memory");
}

// ---------------- cast x (f32) -> bf16 ----------------
__global__ void cast_kernel(const float* __restrict__ x, u16* __restrict__ y, int n4) {
  int i = blockIdx.x * 256 + threadIdx.x;
  if (i >= n4) return;
  const float4 v = reinterpret_cast<const float4*>(x)[i];
  unsigned p0 = (unsigned)f2bf(v.x) | ((unsigned)f2bf(v.y) << 16);
  unsigned p1 = (unsigned)f2bf(v.z) | ((unsigned)f2bf(v.w) << 16);
  reinterpret_cast<uint2*>(y)[i] = make_uint2(p0, p1);
}

// ---------------- fused: all 4 weight transposes (KxN f32 -> NxK bf16) ----------------
__global__ void transpose4_kernel(const float* __restrict__ Wq, const float* __restrict__ Wk,
                                  const float* __restrict__ Wv, const float* __restrict__ Wo,
                                  u16* __restrict__ qkvT, u16* __restrict__ WoT) {
  __shared__ float t[32][33];
  const int m = blockIdx.z;
  const float* W; u16* WT; int N;
  if (m == 0)      { W = Wq; WT = qkvT;                         N = 2048; }
  else if (m == 1) { W = Wk; WT = qkvT + (size_t)2048 * 2048;   N = 512;  }
  else if (m == 2) { W = Wv; WT = qkvT + (size_t)2560 * 2048;   N = 512;  }
  else             { W = Wo; WT = WoT;                          N = 2048; }
  const int n0 = blockIdx.x * 32, k0 = blockIdx.y * 32;
  if (n0 >= N) return;
  const int tx = threadIdx.x, ty = threadIdx.y;
#pragma unroll
  for (int i = 0; i < 32; i += 8)
    t[ty + i][tx] = W[(size_t)(k0 + ty + i) * N + n0 + tx];
  __syncthreads();
#pragma unroll
  for (int i = 0; i < 32; i += 8)
    WT[(size_t)(n0 + ty + i) * 2048 + k0 + tx] = f2bf(t[tx][ty + i]);
}

// ---------------- deep-pipelined GEMM: C(MxN) = A(MxK) @ BT(NxK)^T ----------------
// WRITE_VT: V-region cols (>=2560) are written TRANSPOSED to vt_out instead of C
template<int BM, int BN, int WM, int WN, int EA, int EB, int OUT_BF16, int WRITE_VT>
__global__ __launch_bounds__(512, 1) void gemm_dp(const u16* __restrict__ A, const u16* __restrict__ BT,
                                                  void* __restrict__ Cv, u16* __restrict__ vt_out,
                                                  int M, int N, int K, int nbx) {
  constexpr int PA = BM / 64, PB = BN / 64;
  constexpr int E = EA + EB;
  constexpr int FM = BM / WM / 16, FN = BN / WN / 16;
  static_assert(FM % 2 == 0 && FN % 2 == 0, "quadrant split");
  __shared__ u16 SA[2][BM * 64];
  __shared__ u16 SB[2][BN * 64];
  const int tid = threadIdx.x;
  const int wave = tid >> 6, lane = tid & 63;
  const int lr = lane & 15, lg = lane >> 4;
  const int wm = wave / WN, wn = wave % WN;
  const int nwg = gridDim.x;
  const int bid = blockIdx.x;
  const int swz = (bid & 7) * (nwg >> 3) + (bid >> 3);   // nwg % 8 == 0 (bijective)
  const int bx = swz % nbx, by = swz / nbx;
  const size_t arow0 = (size_t)by * BM;
  const size_t brow0 = (size_t)bx * BN;
  const int NT = K >> 6;

  const int srow = tid >> 3;                       // 0..63 within a 64-row portion
  const int scol = ((tid & 7) ^ (srow & 7)) << 3;  // pre-swizzled source col (elems)

  f32x4 acc[FM][FN] = {};
  bf16x8 af[FM / 2][2], bf0[FN / 2][2], bf1[FN / 2][2];

  const u16* Abase = A + arow0 * K;
  const u16* Bbase = BT + brow0 * K;

  auto stageA = [&](int p, int ktile, int buf) {
    if (ktile >= NT) return;
    const u16* src = Abase + (size_t)(p * 64 + srow) * K + (ktile << 6) + scol;
    ASYNC_COPY16(src, &SA[buf][(p * 64 + wave * 8) * 64]);
  };
  auto stageB = [&](int p, int ktile, int buf) {
    if (ktile >= NT) return;
    const u16* src = Bbase + (size_t)(p * 64 + srow) * K + (ktile << 6) + scol;
    ASYNC_COPY16(src, &SB[buf][(p * 64 + wave * 8) * 64]);
  };
  auto ldA = [&](int c, int mh) {
#pragma unroll
    for (int mf = 0; mf < FM / 2; ++mf)
#pragma unroll
      for (int ks = 0; ks < 2; ++ks) {
        const int row = wm * (BM / WM) + (mh * (FM / 2) + mf) * 16 + lr;
        const int slot = ((ks << 2) | lg) ^ (lr & 7);
        af[mf][ks] = *reinterpret_cast<const bf16x8*>(&SA[c][row * 64 + (slot << 3)]);
      }
  };
  auto ldB = [&](int c, int nh, bf16x8 (*bfr)[2]) {
#pragma unroll
    for (int nf = 0; nf < FN / 2; ++nf)
#pragma unroll
      for (int ks = 0; ks < 2; ++ks) {
        const int row = wn * (BN / WN) + (nh * (FN / 2) + nf) * 16 + lr;
        const int slot = ((ks << 2) | lg) ^ (lr & 7);
        bfr[nf][ks] = *reinterpret_cast<const bf16x8*>(&SB[c][row * 64 + (slot << 3)]);
      }
  };
  auto mq = [&](int mh, int nh, bf16x8 (*bfr)[2]) {
    __builtin_amdgcn_s_setprio(1);
#pragma unroll
    for (int mf = 0; mf < FM / 2; ++mf)
#pragma unroll
      for (int nf = 0; nf < FN / 2; ++nf)
#pragma unroll
        for (int ks = 0; ks < 2; ++ks)
          acc[mh * (FM / 2) + mf][nh * (FN / 2) + nf] = __builtin_amdgcn_mfma_f32_16x16x32_bf16(
              af[mf][ks], bfr[nf][ks], acc[mh * (FM / 2) + mf][nh * (FN / 2) + nf], 0, 0, 0);
    __builtin_amdgcn_s_setprio(0);
  };

  // prologue: all of tile0 -> buf0; early set of tile1 -> buf1
#pragma unroll
  for (int p = 0; p < PA; ++p) stageA(p, 0, 0);
#pragma unroll
  for (int p = 0; p < PB; ++p) stageB(p, 0, 0);
#pragma unroll
  for (int p = 0; p < EB; ++p) stageB(p, 1, 1);
#pragma unroll
  for (int p = 0; p < EA; ++p) stageA(p, 1, 1);
  vmwait<E>();
  BARRIER();

  for (int kt = 0; kt < NT; ++kt) {
    const int c = kt & 1;
    ldA(c, 0); ldB(c, 0, bf0);
#pragma unroll
    for (int p = EB; p < PB; ++p) stageB(p, kt + 1, c ^ 1);
    BARRIER();
    mq(0, 0, bf0);
    BARRIER();
    ldB(c, 1, bf1);
#pragma unroll
    for (int p = EA; p < PA; ++p) stageA(p, kt + 1, c ^ 1);
    BARRIER();
    mq(0, 1, bf1);
    BARRIER();
    ldA(c, 1);
#pragma unroll
    for (int p = 0; p < EB; ++p) stageB(p, kt + 2, c);
    BARRIER();
    mq(1, 1, bf1);
    BARRIER();
#pragma unroll
    for (int p = 0; p < EA; ++p) stageA(p, kt + 2, c);
    BARRIER();
    mq(1, 0, bf0);
    if (kt + 2 < NT) vmwait<E>(); else vmwait<0>();
    BARRIER();
  }

#pragma unroll
  for (int mf = 0; mf < FM; ++mf)
#pragma unroll
    for (int nf = 0; nf < FN; ++nf) {
      const size_t col = brow0 + wn * (BN / WN) + nf * 16 + lr;
      const size_t row0 = arow0 + wm * (BM / WM) + mf * 16 + lg * 4;
      if (WRITE_VT && col >= 2560) {
        const int bb = (int)(row0 >> 11);
        const int t0 = (int)(row0 & 2047);
        u16 tmp[4];
#pragma unroll
        for (int r = 0; r < 4; ++r) tmp[r] = f2bf(acc[mf][nf][r]);
        *reinterpret_cast<uint2*>(vt_out + ((size_t)(bb * 512 + (int)(col - 2560))) * 2048 + t0) =
            *reinterpret_cast<const uint2*>(tmp);
      } else {
#pragma unroll
        for (int r = 0; r < 4; ++r) {
          const size_t row = row0 + r;
          if (OUT_BF16) ((u16*)Cv)[row * N + col] = f2bf(acc[mf][nf][r]);
          else          ((float*)Cv)[row * N + col] = acc[mf][nf][r];
        }
      }
    }
}

// ---------------- RoPE for k only (in place, bf16); q-rope fused into attn ----------------
__global__ void ropek_kernel(u16* __restrict__ qkv, const float* __restrict__ freqs) {
  int idx = blockIdx.x * 256 + threadIdx.x;      // M * NKV * 64 total
  u16* p = qkv + 2048;                            // k slice
  int d = idx & 63;
  int h = (idx >> 6) & 3;
  int row = idx >> 8;
  int t = row & (T_SEQ - 1);
  size_t base = (size_t)row * 3072 + (size_t)h * 128;
  float x1 = bf2f(p[base + d]);
  float x2 = bf2f(p[base + 64 + d]);
  const float* fr = freqs + (size_t)t * 128;
  int dh = d >> 1;
  float c1 = fr[dh],      s1 = fr[64 + dh];
  float c2 = fr[32 + dh], s2 = fr[96 + dh];
  p[base + d]      = f2bf(x1 * c1 - x2 * s1);
  p[base + 64 + d] = f2bf(x2 * c2 + x1 * s2);
}

// ---------------- fused causal GQA flash attention (v9: KVBLK=128, 17 windows) ----------------
// grid (8, NH, B); 512 thr = 8 waves; paired q-tiles {p, 15-p} -> (p+1)+(16-p) = 17
// barrier windows/block (vs 34 at KVBLK=64). K single-buffered [128][136] with
// barrier (B) between QK reads and K-overwrite (v6-verified discipline); V
// double-buffered [2][128][136]; P per-wave [16][136]. LDS 136KB (1 block/CU).
// Staging: 4 thr/row, krow=vrow=tid>>2, c0=(tid&3)*32, 4 x 16B chunks each.
__global__ __launch_bounds__(512) void attn_kernel(const u16* __restrict__ q, const u16* __restrict__ k,
                                                   const u16* __restrict__ vt, u16* __restrict__ o,
                                                   const float* __restrict__ freqs,
                                                   int qstride, int kstride) {
  __shared__ u16 Kl[128][136];      // K tile (single buffer), row=key
  __shared__ u16 Vl[2][128][136];   // V transposed (row=hd, col=key), double buffer
  __shared__ u16 Pl[8][16][136];    // per-wave P tile (16 q-rows x 128 keys)
  const int b = blockIdx.z, h = blockIdx.y, pairIdx = blockIdx.x;
  const int g = h >> 2;
  const int tid = threadIdx.x, wave = tid >> 6, lane = tid & 63;
  const int lr = lane & 15, lg = lane >> 4;

  const float LOG2E = 1.44269504089f;
  const float qk_scale = 0.9f / sqrtf(128.f) * LOG2E;
  const float slope2   = 0.1f * fexp2(-0.5f * (h + 1)) * LOG2E;
  const float THR = 16.0f;

  const int krow = tid >> 2, kc0 = (tid & 3) * 32;   // 128 rows x 128 cols, 4 chunks
  const u16* kbp = k + ((size_t)(b * T_SEQ + krow)) * kstride + g * HEAD_DIM + kc0;
  const u16* vbp = vt + ((size_t)((b * NKV + g) * HEAD_DIM + krow)) * T_SEQ + kc0;

  float cb[8];
#pragma unroll
  for (int nt = 0; nt < 8; ++nt) cb[nt] = slope2 * (float)(nt * 16 + lr);

  for (int half = 0; half < 2; ++half) {
    const int qt = half ? (15 - pairIdx) : pairIdx;
    const int qbase = qt * 128;
    const int trow = qbase + wave * 16 + lr;

    // load raw Q fragments, apply RoPE in-register (lane-local pairs)
    const u16* qp = q + ((size_t)(b * T_SEQ + trow)) * qstride + h * HEAD_DIM;
    bf16x8 qf[4];
#pragma unroll
    for (int ks = 0; ks < 4; ++ks) qf[ks] = *reinterpret_cast<const bf16x8*>(qp + ks * 32 + lg * 8);
    {
      const float* frq = freqs + (size_t)trow * 128;
#pragma unroll
      for (int ks = 0; ks < 2; ++ks)
#pragma unroll
        for (int j = 0; j < 8; ++j) {
          const int dh = (ks * 32 + lg * 8 + j) >> 1;
          float x1 = bf2f((u16)qf[ks][j]);
          float x2 = bf2f((u16)qf[ks + 2][j]);
          qf[ks][j]     = (short)f2bf(x1 * frq[dh]      - x2 * frq[64 + dh]);
          qf[ks + 2][j] = (short)f2bf(x2 * frq[32 + dh] + x1 * frq[96 + dh]);
        }
    }

    f32x4 oa[8] = {};
    float m_r[4], l_r[4];
#pragma unroll
    for (int r = 0; r < 4; ++r) { m_r[r] = -1e30f; l_r[r] = 0.f; }

    const int ktmax = qt;                          // 128-key tiles
    const int irow_min_w = qbase + wave * 16;
    int cur = 0;

    __syncthreads();   // protect previous half's LDS reads
    {
#pragma unroll
      for (int j = 0; j < 4; ++j) {
        bf16x8 kv = *reinterpret_cast<const bf16x8*>(kbp + 8 * j);
        *reinterpret_cast<bf16x8*>(&Kl[krow][kc0 + 8 * j]) = kv;
        bf16x8 vv = *reinterpret_cast<const bf16x8*>(vbp + 8 * j);
        *reinterpret_cast<bf16x8*>(&Vl[0][krow][kc0 + 8 * j]) = vv;
      }
    }

    for (int kt = 0; kt <= ktmax; ++kt) {
      const int kbase = kt * 128;
      __syncthreads();   // (A) staged K/V visible; prior-iter reads drained

      const bool pf = (kt < ktmax);
      bf16x8 pk[4], pv[4];
      if (pf) {
        const u16* ks2p = kbp + (size_t)(kbase + 128) * kstride;
        const u16* vs2p = vbp + kbase + 128;
#pragma unroll
        for (int j = 0; j < 4; ++j) {
          pk[j] = *reinterpret_cast<const bf16x8*>(ks2p + 8 * j);
          pv[j] = *reinterpret_cast<const bf16x8*>(vs2p + 8 * j);
        }
      }

      // S = Q K^T  (16x128 per wave)
      f32x4 sa[8] = {};
#pragma unroll
      for (int nt = 0; nt < 8; ++nt)
#pragma unroll
        for (int ks = 0; ks < 4; ++ks)
          sa[nt] = __builtin_amdgcn_mfma_f32_16x16x32_bf16(
              qf[ks], *reinterpret_cast<const bf16x8*>(&Kl[nt * 16 + lr][ks * 32 + lg * 8]), sa[nt], 0, 0, 0);

      __syncthreads();   // (B) all waves' QK reads of Kl done -> safe to overwrite

      const int i_row0 = irow_min_w + lg * 4;
      const float tb = slope2 * (float)kbase;
      float sv[8][4];
      float pmx[4] = {-1e30f, -1e30f, -1e30f, -1e30f};
      if (kbase + 127 <= irow_min_w) {          // interior: no masking
#pragma unroll
        for (int nt = 0; nt < 8; ++nt) {
          const float bias = cb[nt] + tb;
#pragma unroll
          for (int r = 0; r < 4; ++r) {
            float xv = fmaf(sa[nt][r], qk_scale, bias);
            sv[nt][r] = xv;
            pmx[r] = fmaxf(pmx[r], xv);
          }
        }
      } else {                                  // diagonal: causal mask
#pragma unroll
        for (int nt = 0; nt < 8; ++nt) {
          const int jcol = kbase + nt * 16 + lr;
          const float bias = cb[nt] + tb;
#pragma unroll
          for (int r = 0; r < 4; ++r) {
            float xv = (jcol <= i_row0 + r) ? fmaf(sa[nt][r], qk_scale, bias) : -1e30f;
            sv[nt][r] = xv;
            pmx[r] = fmaxf(pmx[r], xv);
          }
        }
      }

      bool okl = true;
#pragma unroll
      for (int r = 0; r < 4; ++r) okl = okl && (pmx[r] <= m_r[r] + THR);
      if (__all(okl)) {
        float rs[4] = {0.f, 0.f, 0.f, 0.f};
#pragma unroll
        for (int nt = 0; nt < 8; ++nt)
#pragma unroll
          for (int r = 0; r < 4; ++r) {
            float p = fexp2(sv[nt][r] - m_r[r]);
            sv[nt][r] = p;
            rs[r] += p;
          }
#pragma unroll
        for (int r = 0; r < 4; ++r) l_r[r] += rs[r];
      } else {
#pragma unroll
        for (int mm = 1; mm < 16; mm <<= 1)
#pragma unroll
          for (int r = 0; r < 4; ++r) pmx[r] = fmaxf(pmx[r], __shfl_xor(pmx[r], mm, 64));
        float corr[4], rs[4];
#pragma unroll
        for (int r = 0; r < 4; ++r) {
          float mn = fmaxf(m_r[r], pmx[r]);
          corr[r] = fexp2(m_r[r] - mn);
          m_r[r] = mn;
          rs[r] = 0.f;
        }
#pragma unroll
        for (int nt = 0; nt < 8; ++nt)
#pragma unroll
          for (int r = 0; r < 4; ++r) {
            float p = fexp2(sv[nt][r] - m_r[r]);
            sv[nt][r] = p;
            rs[r] += p;
          }
#pragma unroll
        for (int r = 0; r < 4; ++r) l_r[r] = l_r[r] * corr[r] + rs[r];
#pragma unroll
        for (int t8 = 0; t8 < 8; ++t8)
#pragma unroll
          for (int r = 0; r < 4; ++r) oa[t8][r] *= corr[r];
      }

      // P -> wave-local LDS (bf16)
#pragma unroll
      for (int nt = 0; nt < 8; ++nt)
#pragma unroll
        for (int r = 0; r < 4; ++r)
          Pl[wave][lg * 4 + r][nt * 16 + lr] = f2bf(sv[nt][r]);

      // write prefetched tile: K -> Kl (safe after (B)), V -> other buffer
      if (pf) {
#pragma unroll
        for (int j = 0; j < 4; ++j) {
          *reinterpret_cast<bf16x8*>(&Kl[krow][kc0 + 8 * j]) = pk[j];
          *reinterpret_cast<bf16x8*>(&Vl[cur ^ 1][krow][kc0 + 8 * j]) = pv[j];
        }
      }

      // O += P @ V (4 k-slices of 32 keys)
      {
        bf16x8 pa[4];
#pragma unroll
        for (int ks2 = 0; ks2 < 4; ++ks2)
          pa[ks2] = *reinterpret_cast<const bf16x8*>(&Pl[wave][lr][ks2 * 32 + lg * 8]);
#pragma unroll
        for (int ht = 0; ht < 8; ++ht)
#pragma unroll
          for (int ks2 = 0; ks2 < 4; ++ks2) {
            bf16x8 vb8 = *reinterpret_cast<const bf16x8*>(&Vl[cur][ht * 16 + lr][ks2 * 32 + lg * 8]);
            oa[ht] = __builtin_amdgcn_mfma_f32_16x16x32_bf16(pa[ks2], vb8, oa[ht], 0, 0, 0);
          }
      }
      cur ^= 1;
    }

    // epilogue: reduce partial l across the 16-lane column group, store O/l
#pragma unroll
    for (int mm = 1; mm < 16; mm <<= 1)
#pragma unroll
      for (int r = 0; r < 4; ++r) l_r[r] += __shfl_xor(l_r[r], mm, 64);

    u16* op = o + ((size_t)(b * T_SEQ + qbase + wave * 16)) * D_MODEL + h * HEAD_DIM;
#pragma unroll
    for (int r = 0; r < 4; ++r) {
      float inv = 1.0f / l_r[r];
#pragma unroll
      for (int ht = 0; ht < 8; ++ht)
        op[(size_t)(lg * 4 + r) * D_MODEL + ht * 16 + lr] = f2bf(oa[ht][r] * inv);
    }
  }
}

extern "C" void kernel_launch(void* const* d_in, const int* in_sizes, int n_in,
                              void* d_out, int out_size, void* d_ws, size_t ws_size,
                              hipStream_t stream) {
  (void)in_sizes; (void)n_in; (void)out_size; (void)ws_size;
  const float* x     = (const float*)d_in[0];
  const float* freqs = (const float*)d_in[2];
  const float* Wq    = (const float*)d_in[4];
  const float* Wk    = (const float*)d_in[5];
  const float* Wv    = (const float*)d_in[6];
  const float* Wo    = (const float*)d_in[7];
  float* out = (float*)d_out;
  char* ws = (char*)d_ws;
  const size_t MB = 1024 * 1024;
  u16* xb   = (u16*)(ws);            // 16MB  x as bf16; later reused as attn_out
  u16* qkvT = (u16*)(ws + 16 * MB);  // 12MB  [3072][2048] bf16 (Wq|Wk|Wv rows)
  u16* WoT  = (u16*)(ws + 28 * MB);  // 8MB
  u16* qkv  = (u16*)(ws + 36 * MB);  // 24MB  [4096][3072] bf16
  u16* vtb  = (u16*)(ws + 60 * MB);  // 4MB  (written during QKV GEMM)
  const int M = 2 * T_SEQ;           // 4096 rows
  const int NQKV = 3072;

  cast_kernel<<<(M * D_MODEL / 4 + 255) / 256, 256, 0, stream>>>(x, xb, M * D_MODEL / 4);
  dim3 tb(32, 8);
  transpose4_kernel<<<dim3(64, 64, 4), tb, 0, stream>>>(Wq, Wk, Wv, Wo, qkvT, WoT);

  // fused QKV projection + V-transpose epilogue: BM=256, BN=192 -> 256 blocks
  gemm_dp<256, 192, 4, 2, 2, 2, 1, 1><<<256, 512, 0, stream>>>(xb, qkvT, qkv, vtb, M, NQKV, 2048, NQKV / 192);

  // k-only rope (q-rope fused into attn)
  ropek_kernel<<<(M * NKV * 64) / 256, 256, 0, stream>>>(qkv, freqs);

  attn_kernel<<<dim3(8, NH, 2), 512, 0, stream>>>(qkv, qkv + 2048, vtb, xb, freqs, NQKV, NQKV);

  // output projection: BM=128, BN=256 -> 256 blocks (100% CU fill)
  gemm_dp<128, 256, 2, 4, 1, 2, 0, 0><<<256, 512, 0, stream>>>(xb, WoT, out, nullptr, M, 2048, 2048, 2048 / 256);
}

// Round 18
// 207.034 us; speedup vs baseline: 1.0103x; 1.0103x over previous
//
#include <hip/hip_runtime.h>

#define T_SEQ 2048
#define D_MODEL 2048
#define NH 16
#define NKV 4
#define HEAD_DIM 128

typedef unsigned short u16;
typedef __attribute__((ext_vector_type(8))) short bf16x8;
typedef __attribute__((ext_vector_type(4))) float f32x4;

__device__ __forceinline__ float bf2f(u16 u) { return __uint_as_float(((unsigned)u) << 16); }
__device__ __forceinline__ u16 f2bf(float f) {
  unsigned x = __float_as_uint(f);
  return (u16)((x + 0x7FFFu + ((x >> 16) & 1u)) >> 16);
}
__device__ __forceinline__ float fexp2(float x) { return __builtin_amdgcn_exp2f(x); }

#define ASYNC_COPY16(g, l)                                                        \
  __builtin_amdgcn_global_load_lds((const __attribute__((address_space(1))) unsigned int*)(g), \
                                   (__attribute__((address_space(3))) unsigned int*)(l), 16, 0, 0)

#define BARRIER() do { asm volatile("" ::: "memory"); __builtin_amdgcn_s_barrier(); asm volatile("" ::: "memory"); } while (0)

template<int N> __device__ __forceinline__ void vmwait() {
  if constexpr (N == 0) asm volatile("s_waitcnt vmcnt(0)" ::: "memory");
  else if constexpr (N == 3) asm volatile("s_waitcnt vmcnt(3)" ::: "memory");
  else if constexpr (N == 4) asm volatile("s_waitcnt vmcnt(4)" ::: "memory");
  else if constexpr (N == 5) asm volatile("s_waitcnt vmcnt(5)" ::: "memory");
}

// ---------------- cast x (f32) -> bf16 ----------------
__global__ void cast_kernel(const float* __restrict__ x, u16* __restrict__ y, int n4) {
  int i = blockIdx.x * 256 + threadIdx.x;
  if (i >= n4) return;
  const float4 v = reinterpret_cast<const float4*>(x)[i];
  unsigned p0 = (unsigned)f2bf(v.x) | ((unsigned)f2bf(v.y) << 16);
  unsigned p1 = (unsigned)f2bf(v.z) | ((unsigned)f2bf(v.w) << 16);
  reinterpret_cast<uint2*>(y)[i] = make_uint2(p0, p1);
}

// ---------------- fused: all 4 weight transposes (KxN f32 -> NxK bf16) ----------------
__global__ void transpose4_kernel(const float* __restrict__ Wq, const float* __restrict__ Wk,
                                  const float* __restrict__ Wv, const float* __restrict__ Wo,
                                  u16* __restrict__ qkvT, u16* __restrict__ WoT) {
  __shared__ float t[32][33];
  const int m = blockIdx.z;
  const float* W; u16* WT; int N;
  if (m == 0)      { W = Wq; WT = qkvT;                         N = 2048; }
  else if (m == 1) { W = Wk; WT = qkvT + (size_t)2048 * 2048;   N = 512;  }
  else if (m == 2) { W = Wv; WT = qkvT + (size_t)2560 * 2048;   N = 512;  }
  else             { W = Wo; WT = WoT;                          N = 2048; }
  const int n0 = blockIdx.x * 32, k0 = blockIdx.y * 32;
  if (n0 >= N) return;
  const int tx = threadIdx.x, ty = threadIdx.y;
#pragma unroll
  for (int i = 0; i < 32; i += 8)
    t[ty + i][tx] = W[(size_t)(k0 + ty + i) * N + n0 + tx];
  __syncthreads();
#pragma unroll
  for (int i = 0; i < 32; i += 8)
    WT[(size_t)(n0 + ty + i) * 2048 + k0 + tx] = f2bf(t[tx][ty + i]);
}

// ---------------- deep-pipelined GEMM: C(MxN) = A(MxK) @ BT(NxK)^T ----------------
// WRITE_VT: V-region cols (>=2560) are written TRANSPOSED to vt_out instead of C
// (b,g,hd,t layout) -- replaces the standalone vt_kernel. Bit-identical values.
template<int BM, int BN, int WM, int WN, int EA, int EB, int OUT_BF16, int WRITE_VT>
__global__ __launch_bounds__(512, 1) void gemm_dp(const u16* __restrict__ A, const u16* __restrict__ BT,
                                                  void* __restrict__ Cv, u16* __restrict__ vt_out,
                                                  int M, int N, int K, int nbx) {
  constexpr int PA = BM / 64, PB = BN / 64;
  constexpr int E = EA + EB;
  constexpr int FM = BM / WM / 16, FN = BN / WN / 16;
  static_assert(FM % 2 == 0 && FN % 2 == 0, "quadrant split");
  __shared__ u16 SA[2][BM * 64];
  __shared__ u16 SB[2][BN * 64];
  const int tid = threadIdx.x;
  const int wave = tid >> 6, lane = tid & 63;
  const int lr = lane & 15, lg = lane >> 4;
  const int wm = wave / WN, wn = wave % WN;
  const int nwg = gridDim.x;
  const int bid = blockIdx.x;
  const int swz = (bid & 7) * (nwg >> 3) + (bid >> 3);   // nwg % 8 == 0 (bijective)
  const int bx = swz % nbx, by = swz / nbx;
  const size_t arow0 = (size_t)by * BM;
  const size_t brow0 = (size_t)bx * BN;
  const int NT = K >> 6;

  const int srow = tid >> 3;                       // 0..63 within a 64-row portion
  const int scol = ((tid & 7) ^ (srow & 7)) << 3;  // pre-swizzled source col (elems)

  f32x4 acc[FM][FN] = {};
  bf16x8 af[FM / 2][2], bf0[FN / 2][2], bf1[FN / 2][2];

  const u16* Abase = A + arow0 * K;
  const u16* Bbase = BT + brow0 * K;

  auto stageA = [&](int p, int ktile, int buf) {
    if (ktile >= NT) return;
    const u16* src = Abase + (size_t)(p * 64 + srow) * K + (ktile << 6) + scol;
    ASYNC_COPY16(src, &SA[buf][(p * 64 + wave * 8) * 64]);
  };
  auto stageB = [&](int p, int ktile, int buf) {
    if (ktile >= NT) return;
    const u16* src = Bbase + (size_t)(p * 64 + srow) * K + (ktile << 6) + scol;
    ASYNC_COPY16(src, &SB[buf][(p * 64 + wave * 8) * 64]);
  };
  auto ldA = [&](int c, int mh) {
#pragma unroll
    for (int mf = 0; mf < FM / 2; ++mf)
#pragma unroll
      for (int ks = 0; ks < 2; ++ks) {
        const int row = wm * (BM / WM) + (mh * (FM / 2) + mf) * 16 + lr;
        const int slot = ((ks << 2) | lg) ^ (lr & 7);
        af[mf][ks] = *reinterpret_cast<const bf16x8*>(&SA[c][row * 64 + (slot << 3)]);
      }
  };
  auto ldB = [&](int c, int nh, bf16x8 (*bfr)[2]) {
#pragma unroll
    for (int nf = 0; nf < FN / 2; ++nf)
#pragma unroll
      for (int ks = 0; ks < 2; ++ks) {
        const int row = wn * (BN / WN) + (nh * (FN / 2) + nf) * 16 + lr;
        const int slot = ((ks << 2) | lg) ^ (lr & 7);
        bfr[nf][ks] = *reinterpret_cast<const bf16x8*>(&SB[c][row * 64 + (slot << 3)]);
      }
  };
  auto mq = [&](int mh, int nh, bf16x8 (*bfr)[2]) {
    __builtin_amdgcn_s_setprio(1);
#pragma unroll
    for (int mf = 0; mf < FM / 2; ++mf)
#pragma unroll
      for (int nf = 0; nf < FN / 2; ++nf)
#pragma unroll
        for (int ks = 0; ks < 2; ++ks)
          acc[mh * (FM / 2) + mf][nh * (FN / 2) + nf] = __builtin_amdgcn_mfma_f32_16x16x32_bf16(
              af[mf][ks], bfr[nf][ks], acc[mh * (FM / 2) + mf][nh * (FN / 2) + nf], 0, 0, 0);
    __builtin_amdgcn_s_setprio(0);
  };

  // prologue: all of tile0 -> buf0; early set of tile1 -> buf1
#pragma unroll
  for (int p = 0; p < PA; ++p) stageA(p, 0, 0);
#pragma unroll
  for (int p = 0; p < PB; ++p) stageB(p, 0, 0);
#pragma unroll
  for (int p = 0; p < EB; ++p) stageB(p, 1, 1);
#pragma unroll
  for (int p = 0; p < EA; ++p) stageA(p, 1, 1);
  vmwait<E>();
  BARRIER();

  for (int kt = 0; kt < NT; ++kt) {
    const int c = kt & 1;
    ldA(c, 0); ldB(c, 0, bf0);
#pragma unroll
    for (int p = EB; p < PB; ++p) stageB(p, kt + 1, c ^ 1);
    BARRIER();
    mq(0, 0, bf0);
    BARRIER();
    ldB(c, 1, bf1);
#pragma unroll
    for (int p = EA; p < PA; ++p) stageA(p, kt + 1, c ^ 1);
    BARRIER();
    mq(0, 1, bf1);
    BARRIER();
    ldA(c, 1);
#pragma unroll
    for (int p = 0; p < EB; ++p) stageB(p, kt + 2, c);
    BARRIER();
    mq(1, 1, bf1);
    BARRIER();
#pragma unroll
    for (int p = 0; p < EA; ++p) stageA(p, kt + 2, c);
    BARRIER();
    mq(1, 0, bf0);
    if (kt + 2 < NT) vmwait<E>(); else vmwait<0>();
    BARRIER();
  }

#pragma unroll
  for (int mf = 0; mf < FM; ++mf)
#pragma unroll
    for (int nf = 0; nf < FN; ++nf) {
      const size_t col = brow0 + wn * (BN / WN) + nf * 16 + lr;
      const size_t row0 = arow0 + wm * (BM / WM) + mf * 16 + lg * 4;
      if (WRITE_VT && col >= 2560) {
        // V region: write transposed to vt_out[(b*512 + (col-2560))*2048 + t]
        // 4 consecutive rows -> 4 consecutive t -> one aligned 8B store
        const int bb = (int)(row0 >> 11);
        const int t0 = (int)(row0 & 2047);
        u16 tmp[4];
#pragma unroll
        for (int r = 0; r < 4; ++r) tmp[r] = f2bf(acc[mf][nf][r]);
        *reinterpret_cast<uint2*>(vt_out + ((size_t)(bb * 512 + (int)(col - 2560))) * 2048 + t0) =
            *reinterpret_cast<const uint2*>(tmp);
      } else {
#pragma unroll
        for (int r = 0; r < 4; ++r) {
          const size_t row = row0 + r;
          if (OUT_BF16) ((u16*)Cv)[row * N + col] = f2bf(acc[mf][nf][r]);
          else          ((float*)Cv)[row * N + col] = acc[mf][nf][r];
        }
      }
    }
}

// ---------------- RoPE for k only (in place, bf16); q-rope fused into attn ----------------
__global__ void ropek_kernel(u16* __restrict__ qkv, const float* __restrict__ freqs) {
  int idx = blockIdx.x * 256 + threadIdx.x;      // M * NKV * 64 total
  u16* p = qkv + 2048;                            // k slice
  int d = idx & 63;
  int h = (idx >> 6) & 3;
  int row = idx >> 8;
  int t = row & (T_SEQ - 1);
  size_t base = (size_t)row * 3072 + (size_t)h * 128;
  float x1 = bf2f(p[base + d]);
  float x2 = bf2f(p[base + 64 + d]);
  const float* fr = freqs + (size_t)t * 128;
  int dh = d >> 1;
  float c1 = fr[dh],      s1 = fr[64 + dh];
  float c2 = fr[32 + dh], s2 = fr[96 + dh];
  p[base + d]      = f2bf(x1 * c1 - x2 * s1);
  p[base + 64 + d] = f2bf(x2 * c2 + x1 * s2);
}

// ---------------- fused causal GQA flash attention (v3 + fused Q-rope) ----------------
// grid (8, NH, B); 512 thr = 8 waves; paired q-tiles {p, 15-p}: 34 KV tiles/block.
// Q-rope applied in-register at fragment load: pair (d, d+64) is lane-local
// (qf[ks][j] <-> qf[ks+2][j], d = ks*32+lg*8+j), identical math to rope kernel.
__global__ __launch_bounds__(512) void attn_kernel(const u16* __restrict__ q, const u16* __restrict__ k,
                                                   const u16* __restrict__ vt, u16* __restrict__ o,
                                                   const float* __restrict__ freqs,
                                                   int qstride, int kstride) {
  __shared__ u16 Kl[2][64][136];
  __shared__ u16 Vl[2][128][72];
  __shared__ u16 Pl[8][16][72];
  const int b = blockIdx.z, h = blockIdx.y, pairIdx = blockIdx.x;
  const int g = h >> 2;
  const int tid = threadIdx.x, wave = tid >> 6, lane = tid & 63;
  const int lr = lane & 15, lg = lane >> 4;

  const float LOG2E = 1.44269504089f;
  const float qk_scale = 0.9f / sqrtf(128.f) * LOG2E;
  const float slope2   = 0.1f * fexp2(-0.5f * (h + 1)) * LOG2E;
  const float THR = 16.0f;

  const int krow = tid >> 3, kc0 = (tid & 7) * 16;
  const int vrow = tid >> 2, vc0 = (tid & 3) * 16;
  const u16* kbp = k + ((size_t)(b * T_SEQ + krow)) * kstride + g * HEAD_DIM + kc0;
  const u16* vbp = vt + ((size_t)((b * NKV + g) * HEAD_DIM + vrow)) * T_SEQ + vc0;

  float cb[4];
#pragma unroll
  for (int nt = 0; nt < 4; ++nt) cb[nt] = slope2 * (float)(nt * 16 + lr);

  for (int half = 0; half < 2; ++half) {
    const int qt = half ? (15 - pairIdx) : pairIdx;
    const int qbase = qt * 128;
    const int trow = qbase + wave * 16 + lr;      // q row in [0, T_SEQ)

    // load raw Q fragments, apply RoPE in-register (lane-local pairs)
    const u16* qp = q + ((size_t)(b * T_SEQ + trow)) * qstride + h * HEAD_DIM;
    bf16x8 qf[4];
#pragma unroll
    for (int ks = 0; ks < 4; ++ks) qf[ks] = *reinterpret_cast<const bf16x8*>(qp + ks * 32 + lg * 8);
    {
      const float* frq = freqs + (size_t)trow * 128;
#pragma unroll
      for (int ks = 0; ks < 2; ++ks)
#pragma unroll
        for (int j = 0; j < 8; ++j) {
          const int dh = (ks * 32 + lg * 8 + j) >> 1;
          float x1 = bf2f((u16)qf[ks][j]);
          float x2 = bf2f((u16)qf[ks + 2][j]);
          qf[ks][j]     = (short)f2bf(x1 * frq[dh]      - x2 * frq[64 + dh]);
          qf[ks + 2][j] = (short)f2bf(x2 * frq[32 + dh] + x1 * frq[96 + dh]);
        }
    }

    f32x4 oa[8] = {};
    float m_r[4], l_r[4];
#pragma unroll
    for (int r = 0; r < 4; ++r) { m_r[r] = -1e30f; l_r[r] = 0.f; }

    const int ktmax = 2 * qt + 1;
    const int irow_min_w = qbase + wave * 16;
    const int irow_max_w = irow_min_w + 15;
    int cur = 0;

    __syncthreads();
    {
      bf16x8 k0a = *reinterpret_cast<const bf16x8*>(kbp);
      bf16x8 k0b = *reinterpret_cast<const bf16x8*>(kbp + 8);
      bf16x8 v0a = *reinterpret_cast<const bf16x8*>(vbp);
      bf16x8 v0b = *reinterpret_cast<const bf16x8*>(vbp + 8);
      *reinterpret_cast<bf16x8*>(&Kl[0][krow][kc0]) = k0a;
      *reinterpret_cast<bf16x8*>(&Kl[0][krow][kc0 + 8]) = k0b;
      *reinterpret_cast<bf16x8*>(&Vl[0][vrow][vc0]) = v0a;
      *reinterpret_cast<bf16x8*>(&Vl[0][vrow][vc0 + 8]) = v0b;
    }

    for (int kt = 0; kt <= ktmax; ++kt) {
      const int kbase = kt * 64;
      __syncthreads();

      const bool pf = (kt < ktmax);
      bf16x8 pk0, pk1, pv0, pv1;
      if (pf) {
        const u16* ks2p = kbp + (size_t)(kbase + 64) * kstride;
        pk0 = *reinterpret_cast<const bf16x8*>(ks2p);
        pk1 = *reinterpret_cast<const bf16x8*>(ks2p + 8);
        const u16* vs2p = vbp + kbase + 64;
        pv0 = *reinterpret_cast<const bf16x8*>(vs2p);
        pv1 = *reinterpret_cast<const bf16x8*>(vs2p + 8);
      }

      const bool compute = (kbase <= irow_max_w);
      if (compute) {
        f32x4 sa[4] = {};
#pragma unroll
        for (int nt = 0; nt < 4; ++nt)
#pragma unroll
          for (int ks = 0; ks < 4; ++ks)
            sa[nt] = __builtin_amdgcn_mfma_f32_16x16x32_bf16(
                qf[ks], *reinterpret_cast<const bf16x8*>(&Kl[cur][nt * 16 + lr][ks * 32 + lg * 8]), sa[nt], 0, 0, 0);

        const int i_row0 = irow_min_w + lg * 4;
        const float tb = slope2 * (float)kbase;
        float sv[4][4];
        float pmx[4] = {-1e30f, -1e30f, -1e30f, -1e30f};
        if (kbase + 63 <= irow_min_w) {
#pragma unroll
          for (int nt = 0; nt < 4; ++nt) {
            const float bias = cb[nt] + tb;
#pragma unroll
            for (int r = 0; r < 4; ++r) {
              float xv = fmaf(sa[nt][r], qk_scale, bias);
              sv[nt][r] = xv;
              pmx[r] = fmaxf(pmx[r], xv);
            }
          }
        } else {
#pragma unroll
          for (int nt = 0; nt < 4; ++nt) {
            const int jcol = kbase + nt * 16 + lr;
            const float bias = cb[nt] + tb;
#pragma unroll
            for (int r = 0; r < 4; ++r) {
              float xv = (jcol <= i_row0 + r) ? fmaf(sa[nt][r], qk_scale, bias) : -1e30f;
              sv[nt][r] = xv;
              pmx[r] = fmaxf(pmx[r], xv);
            }
          }
        }

        bool okl = true;
#pragma unroll
        for (int r = 0; r < 4; ++r) okl = okl && (pmx[r] <= m_r[r] + THR);
        if (__all(okl)) {
          float rs[4] = {0.f, 0.f, 0.f, 0.f};
#pragma unroll
          for (int nt = 0; nt < 4; ++nt)
#pragma unroll
            for (int r = 0; r < 4; ++r) {
              float p = fexp2(sv[nt][r] - m_r[r]);
              sv[nt][r] = p;
              rs[r] += p;
            }
#pragma unroll
          for (int r = 0; r < 4; ++r) l_r[r] += rs[r];
        } else {
#pragma unroll
          for (int mm = 1; mm < 16; mm <<= 1)
#pragma unroll
            for (int r = 0; r < 4; ++r) pmx[r] = fmaxf(pmx[r], __shfl_xor(pmx[r], mm, 64));
          float corr[4], rs[4];
#pragma unroll
          for (int r = 0; r < 4; ++r) {
            float mn = fmaxf(m_r[r], pmx[r]);
            corr[r] = fexp2(m_r[r] - mn);
            m_r[r] = mn;
            rs[r] = 0.f;
          }
#pragma unroll
          for (int nt = 0; nt < 4; ++nt)
#pragma unroll
            for (int r = 0; r < 4; ++r) {
              float p = fexp2(sv[nt][r] - m_r[r]);
              sv[nt][r] = p;
              rs[r] += p;
            }
#pragma unroll
          for (int r = 0; r < 4; ++r) l_r[r] = l_r[r] * corr[r] + rs[r];
#pragma unroll
          for (int t8 = 0; t8 < 8; ++t8)
#pragma unroll
            for (int r = 0; r < 4; ++r) oa[t8][r] *= corr[r];
        }

#pragma unroll
        for (int nt = 0; nt < 4; ++nt)
#pragma unroll
          for (int r = 0; r < 4; ++r)
            Pl[wave][lg * 4 + r][nt * 16 + lr] = f2bf(sv[nt][r]);
      }

      if (pf) {
        *reinterpret_cast<bf16x8*>(&Kl[cur ^ 1][krow][kc0]) = pk0;
        *reinterpret_cast<bf16x8*>(&Kl[cur ^ 1][krow][kc0 + 8]) = pk1;
        *reinterpret_cast<bf16x8*>(&Vl[cur ^ 1][vrow][vc0]) = pv0;
        *reinterpret_cast<bf16x8*>(&Vl[cur ^ 1][vrow][vc0 + 8]) = pv1;
      }

      if (compute) {
#pragma unroll
        for (int ht = 0; ht < 8; ++ht)
#pragma unroll
          for (int ks2 = 0; ks2 < 2; ++ks2) {
            bf16x8 pa = *reinterpret_cast<const bf16x8*>(&Pl[wave][lr][ks2 * 32 + lg * 8]);
            bf16x8 vb8 = *reinterpret_cast<const bf16x8*>(&Vl[cur][ht * 16 + lr][ks2 * 32 + lg * 8]);
            oa[ht] = __builtin_amdgcn_mfma_f32_16x16x32_bf16(pa, vb8, oa[ht], 0, 0, 0);
          }
      }
      cur ^= 1;
    }

#pragma unroll
    for (int mm = 1; mm < 16; mm <<= 1)
#pragma unroll
      for (int r = 0; r < 4; ++r) l_r[r] += __shfl_xor(l_r[r], mm, 64);

    u16* op = o + ((size_t)(b * T_SEQ + qbase + wave * 16)) * D_MODEL + h * HEAD_DIM;
#pragma unroll
    for (int r = 0; r < 4; ++r) {
      float inv = 1.0f / l_r[r];
#pragma unroll
      for (int ht = 0; ht < 8; ++ht)
        op[(size_t)(lg * 4 + r) * D_MODEL + ht * 16 + lr] = f2bf(oa[ht][r] * inv);
    }
  }
}

extern "C" void kernel_launch(void* const* d_in, const int* in_sizes, int n_in,
                              void* d_out, int out_size, void* d_ws, size_t ws_size,
                              hipStream_t stream) {
  (void)in_sizes; (void)n_in; (void)out_size; (void)ws_size;
  const float* x     = (const float*)d_in[0];
  const float* freqs = (const float*)d_in[2];
  const float* Wq    = (const float*)d_in[4];
  const float* Wk    = (const float*)d_in[5];
  const float* Wv    = (const float*)d_in[6];
  const float* Wo    = (const float*)d_in[7];
  float* out = (float*)d_out;
  char* ws = (char*)d_ws;
  const size_t MB = 1024 * 1024;
  u16* xb   = (u16*)(ws);            // 16MB  x as bf16; later reused as attn_out
  u16* qkvT = (u16*)(ws + 16 * MB);  // 12MB  [3072][2048] bf16 (Wq|Wk|Wv rows)
  u16* WoT  = (u16*)(ws + 28 * MB);  // 8MB
  u16* qkv  = (u16*)(ws + 36 * MB);  // 24MB  [4096][3072] bf16
  u16* vtb  = (u16*)(ws + 60 * MB);  // 4MB  (must NOT overlap qkvT: written during QKV GEMM)
  const int M = 2 * T_SEQ;           // 4096 rows
  const int NQKV = 3072;

  cast_kernel<<<(M * D_MODEL / 4 + 255) / 256, 256, 0, stream>>>(x, xb, M * D_MODEL / 4);
  dim3 tb(32, 8);
  transpose4_kernel<<<dim3(64, 64, 4), tb, 0, stream>>>(Wq, Wk, Wv, Wo, qkvT, WoT);

  // fused QKV projection + V-transpose epilogue: BM=256, BN=192 -> 256 blocks
  gemm_dp<256, 192, 4, 2, 2, 2, 1, 1><<<256, 512, 0, stream>>>(xb, qkvT, qkv, vtb, M, NQKV, 2048, NQKV / 192);

  // k-only rope (q-rope fused into attn)
  ropek_kernel<<<(M * NKV * 64) / 256, 256, 0, stream>>>(qkv, freqs);

  attn_kernel<<<dim3(8, NH, 2), 512, 0, stream>>>(qkv, qkv + 2048, vtb, xb, freqs, NQKV, NQKV);

  // output projection: BM=128, BN=256 -> 256 blocks (100% CU fill)
  gemm_dp<128, 256, 2, 4, 1, 2, 0, 0><<<256, 512, 0, stream>>>(xb, WoT, out, nullptr, M, 2048, 2048, 2048 / 256);
}